// Round 12
// baseline (601.705 us; speedup 1.0000x reference)
//
#include <hip/hip_runtime.h>
#include <cstdio>

#define NTOK 8192
#define DIM 1024
#define HID 2048
#define NE 8
#define NPAIR (NTOK * 2)

typedef __attribute__((ext_vector_type(8))) short bf16x8;
typedef __attribute__((ext_vector_type(4))) float f32x4;

typedef const __attribute__((address_space(1))) void* gas_ptr;
typedef __attribute__((address_space(3))) void* las_ptr;

__device__ __forceinline__ void async16(const void* g, void* s) {
  // direct global->LDS, 16B per lane; LDS dest = wave-uniform base + lane*16
  __builtin_amdgcn_global_load_lds((gas_ptr)g, (las_ptr)s, 16, 0, 0);
}

__device__ __forceinline__ unsigned short f2bf(float f) {
  unsigned int u = __float_as_uint(f);
  u = (u + 0x7fff + ((u >> 16) & 1)) >> 16;  // RNE
  return (unsigned short)u;
}

__device__ __forceinline__ float bf2f(unsigned short u) {
  return __uint_as_float((unsigned int)u << 16);
}

// r17: restore r14-best GEMM structure (de-pinned depth-4 = 183us stage1;
// ledger: pinned-d4 198 / de-pinned-d4 183 / 2-phase 202 / depth-2 206) +
// ONE new lever: intra-expert dispatch order ytile-fastest. Old order
// (ytile-major, h0-minor) made the ~32 resident blocks/XCD span 16 h0
// W-panels = 8MB > 4MB L2 -> weights thrash, re-fetched per ytile pass
// (FETCH 168 vs ~82 ideal). ytile-fastest: resident blocks share 1-2
// h0-groups (W set ~1MB, L2-resident, fetched ~once); X re-read from L2/L3.
// r13 slope (0.36us/MB) predicts ~-25us on stage1. Expert-pinning kept.

#define S_BARRIER __builtin_amdgcn_s_barrier()
#define VM_WAIT(N) asm volatile("s_waitcnt vmcnt(" #N ")" ::: "memory")
#define LGKM0 asm volatile("s_waitcnt lgkmcnt(0)" ::: "memory")
#define CFENCE asm volatile("" ::: "memory")

// ---------------------------------------------------------------------------
// prepgate: fused prep (blocks 0..12287) + gate (blocks 12288..14335).
// ---------------------------------------------------------------------------
__global__ __launch_bounds__(256) void prepgate_kernel(
    const float* __restrict__ w1, const float* __restrict__ w2,
    const float* __restrict__ w3, unsigned short* __restrict__ w1bt,
    unsigned short* __restrict__ w2bt, unsigned short* __restrict__ w3bt,
    const float* __restrict__ x, const float* __restrict__ gw,
    const float* __restrict__ gb, unsigned short* __restrict__ xb,
    float* __restrict__ scores, int* __restrict__ route_e,
    float* __restrict__ route_w) {
  __shared__ float smem[NE * DIM];  // 32 KB union: prep tT[64][65], gate sgwT
  const int bx = blockIdx.x;
  const int tid = threadIdx.x;

  if (bx < 12288) {
    // ---- prep path ----
    float (*tT)[65] = reinterpret_cast<float(*)[65]>(smem);
    const int z = bx >> 9;     // 0..23
    const int bxx = bx & 511;
    const int m = z >> 3, e = z & 7;
    int R, C;
    const float* in;
    unsigned short* outp;
    if (m == 0)      { R = DIM; C = HID; in = w1; outp = w1bt; }
    else if (m == 1) { R = DIM; C = HID; in = w2; outp = w2bt; }
    else             { R = HID; C = DIM; in = w3; outp = w3bt; }
    in += (size_t)e * DIM * HID;
    outp += (size_t)e * DIM * HID;

    const int tilesx = C >> 6;
    const int c0 = (bxx % tilesx) * 64;
    const int r0 = (bxx / tilesx) * 64;

    const int cq = tid & 15;   // float4-col index
    const int rr = tid >> 4;   // 0..15
#pragma unroll
    for (int p = 0; p < 4; p++) {
      const int r = rr + p * 16;
      const float4 v = *(const float4*)(in + (size_t)(r0 + r) * C + c0 + cq * 4);
      tT[cq * 4 + 0][r] = v.x;
      tT[cq * 4 + 1][r] = v.y;
      tT[cq * 4 + 2][r] = v.z;
      tT[cq * 4 + 3][r] = v.w;
    }
    __syncthreads();
    // store: thread handles 8 consecutive r-cols of one output row -> 16B
    const int cc8 = tid & 7;   // 8-col group
    const int rr2 = tid >> 3;  // 0..31
#pragma unroll
    for (int p = 0; p < 2; p++) {
      const int cc = rr2 + p * 32;  // output row (= original col)
      bf16x8 o;
#pragma unroll
      for (int k = 0; k < 8; k++) o[k] = (short)f2bf(tT[cc][cc8 * 8 + k]);
      *(bf16x8*)(outp + (size_t)(c0 + cc) * R + r0 + cc8 * 8) = o;
    }
    return;
  }

  // ---- gate path ----
  float (*sgwT)[DIM] = reinterpret_cast<float(*)[DIM]>(smem);  // [NE][DIM]
  const int g = bx - 12288;
#pragma unroll
  for (int i = 0; i < 8; i++) {
    const int j = i * 256 + tid;               // float4 index into gw[DIM][NE]
    const float4 v = ((const float4*)gw)[j];
    const int d = j >> 1, e0 = (j & 1) * 4;    // 2-way bank alias on store: free
    sgwT[e0 + 0][d] = v.x; sgwT[e0 + 1][d] = v.y;
    sgwT[e0 + 2][d] = v.z; sgwT[e0 + 3][d] = v.w;
  }
  __syncthreads();

  const int wv = tid >> 6, lane = tid & 63;
  const int t = g * 4 + wv;
  float acc[NE] = {0.f, 0.f, 0.f, 0.f, 0.f, 0.f, 0.f, 0.f};
  const float4* x4 = (const float4*)(x + (size_t)t * DIM);
#pragma unroll
  for (int i = 0; i < 4; i++) {
    const float4 xv = x4[i * 64 + lane];
    const int d4 = i * 64 + lane;
    ushort4 xbv;
    xbv.x = f2bf(xv.x); xbv.y = f2bf(xv.y);
    xbv.z = f2bf(xv.z); xbv.w = f2bf(xv.w);
    *(ushort4*)(xb + (size_t)t * DIM + d4 * 4) = xbv;
#pragma unroll
    for (int e = 0; e < NE; e++) {
      const float4 wv4 = *(const float4*)&sgwT[e][d4 * 4];  // ds_read_b128
      acc[e] += xv.x * wv4.x + xv.y * wv4.y + xv.z * wv4.z + xv.w * wv4.w;
    }
  }
#pragma unroll
  for (int e = 0; e < NE; e++)
#pragma unroll
    for (int s = 32; s; s >>= 1) acc[e] += __shfl_xor(acc[e], s, 64);

  if (lane == 0) {
    float l[NE], m = -1e30f;
#pragma unroll
    for (int e = 0; e < NE; e++) { l[e] = acc[e] + gb[e]; m = fmaxf(m, l[e]); }
    float p[NE], sum = 0.f;
#pragma unroll
    for (int e = 0; e < NE; e++) { p[e] = __expf(l[e] - m); sum += p[e]; }
    const float inv = 1.f / sum;
    float s[NE];
#pragma unroll
    for (int e = 0; e < NE; e++) { s[e] = p[e] * inv; scores[t * NE + e] = s[e]; }
    int i1 = 0;
    for (int e = 1; e < NE; e++) if (s[e] > s[i1]) i1 = e;
    int i2 = -1;
    for (int e = 0; e < NE; e++) {
      if (e == i1) continue;
      if (i2 < 0 || s[e] > s[i2]) i2 = e;
    }
    route_e[t * 2] = i1; route_e[t * 2 + 1] = i2;
    route_w[t * 2] = s[i1]; route_w[t * 2 + 1] = s[i2];
  }
}

// ---------------------------------------------------------------------------
// finalize: usage -> lb_loss (d_out tail); counts via route_e histogram;
// prefix offsets; cursors. Writes every ctrl field (no memset needed).
// ---------------------------------------------------------------------------
__global__ void finalize_kernel(const float* __restrict__ scores,
                                const int* __restrict__ route_e,
                                int* __restrict__ ctrl,
                                float* __restrict__ out_lb) {
  __shared__ float red[1024];
  __shared__ int hist[NE];
  const int tid = threadIdx.x;
  if (tid < NE) hist[tid] = 0;
  const int e = tid & 7, row = tid >> 3;
  float s = 0.f;
  for (int i = 0; i < 64; i++) s += scores[(size_t)(row + i * 128) * NE + e];
  red[tid] = s;
  __syncthreads();  // hist zero + red visible
#pragma unroll
  for (int i = 0; i < 16; i++)
    atomicAdd(&hist[route_e[i * 1024 + tid]], 1);
  for (int st = 512; st >= 8; st >>= 1) {
    __syncthreads();
    if (tid < st) red[tid] += red[tid + st];
  }
  __syncthreads();
  if (tid == 0) {
    float lb = 0.f;
    for (int ee = 0; ee < NE; ee++) {
      const float u = red[ee] * (1.f / 8192.f);
      lb -= u * __logf(u + 1e-9f);
    }
    *out_lb = lb;
    int o = 0;
    for (int ee = 0; ee < NE; ee++) {
      ctrl[ee] = hist[ee];    // counts
      ctrl[8 + ee] = o;       // offsets
      ctrl[17 + ee] = o;      // cursors
      o += hist[ee];
    }
    ctrl[16] = o;
  }
}

// ---------------------------------------------------------------------------
// scatter: per-block LDS histogram -> 8 global atomics per block.
// ---------------------------------------------------------------------------
__global__ __launch_bounds__(256) void scatter_kernel(
    const int* __restrict__ route_e, const float* __restrict__ route_w,
    int* __restrict__ ctrl, int* __restrict__ tok_list,
    float* __restrict__ pair_w, int* __restrict__ pair_pos) {
  __shared__ int lh[NE];
  __shared__ int lbase[NE];
  const int tid = threadIdx.x;
  const int t = blockIdx.x * 256 + tid;
  if (tid < NE) lh[tid] = 0;
  __syncthreads();
  const int e0 = route_e[t * 2], e1 = route_e[t * 2 + 1];
  const int p0 = atomicAdd(&lh[e0], 1);
  const int p1 = atomicAdd(&lh[e1], 1);  // e1 != e0 (top-2 distinct)
  __syncthreads();
  if (tid < NE) lbase[tid] = atomicAdd(&ctrl[17 + tid], lh[tid]);
  __syncthreads();
  const int q0 = lbase[e0] + p0;
  const int q1 = lbase[e1] + p1;
  tok_list[q0] = t;
  pair_w[q0] = route_w[t * 2] * 0.70710678118654752f;
  pair_pos[t * 2] = q0;
  tok_list[q1] = t;
  pair_w[q1] = route_w[t * 2 + 1] * 0.70710678118654752f;
  pair_pos[t * 2 + 1] = q1;
}

// ---------------------------------------------------------------------------
// stage1 (FUSED): act = (X@W1+b1) * silu(X@W2+b2) for routed rows (bf16)
// 1-D grid 4096, block 512, expert-pinned XCD swizzle, YTILE-FASTEST
// intra-expert order (W-panels L2-resident). M=256 x N=128 tile, BK=32,
// depth-4 counted-vmcnt pipeline, de-pinned MFMA scheduling (r14 = 183us).
// ---------------------------------------------------------------------------
__global__ __launch_bounds__(512) void stage1_kernel(
    const unsigned short* __restrict__ xb, const unsigned short* __restrict__ w1bt,
    const unsigned short* __restrict__ w2bt, const float* __restrict__ b1,
    const float* __restrict__ b2, const int* __restrict__ tok_list,
    const int* __restrict__ ctrl, unsigned short* __restrict__ act) {
  const int hbid = blockIdx.x;
  const int lid = ((hbid & 7) << 9) + (hbid >> 3);  // expert-pinned per XCD
  const int e = lid >> 9;
  const int s = lid & 511;
  const int ytile = s & 31;          // fastest: resident blocks share h0-group
  const int h0 = (s >> 5) * 128;

  const int cnt = ctrl[e];
  if (ytile * 256 >= cnt) return;
  const int off = ctrl[8 + e];
  const int rows = min(256, cnt - ytile * 256);

  __shared__ unsigned short sX[4][256 * 32];   // 64 KB
  __shared__ unsigned short sW1[4][128 * 32];  // 32 KB
  __shared__ unsigned short sW2[4][128 * 32];  // 32 KB

  const int tid = threadIdx.x;
  const int wv = tid >> 6, lane = tid & 63;
  const int cl = ((tid & 3) ^ ((tid >> 3) & 3)) * 8;  // swizzled k-offset

  const unsigned short* w1p = w1bt + (size_t)e * HID * DIM + (size_t)h0 * DIM;
  const unsigned short* w2p = w2bt + (size_t)e * HID * DIM + (size_t)h0 * DIM;
  const unsigned short* gx0 =
      xb + (size_t)tok_list[off + ytile * 256 + min(tid >> 2, rows - 1)] * DIM + cl;
  const unsigned short* gx1 =
      xb + (size_t)tok_list[off + ytile * 256 + min(128 + (tid >> 2), rows - 1)] * DIM + cl;
  const unsigned short* gw1 = w1p + (size_t)(tid >> 2) * DIM + cl;
  const unsigned short* gw2 = w2p + (size_t)(tid >> 2) * DIM + cl;

  f32x4 ah[8][2], ag[8][2];
#pragma unroll
  for (int i = 0; i < 8; i++)
#pragma unroll
    for (int j2 = 0; j2 < 2; j2++) {
      ah[i][j2] = (f32x4){0.f, 0.f, 0.f, 0.f};
      ag[i][j2] = (f32x4){0.f, 0.f, 0.f, 0.f};
    }

  const int wr = wv >> 2, wc = wv & 3;
  const int l15 = lane & 15, q = lane >> 4;
  const int pch = (q ^ ((l15 >> 1) & 3)) * 8;

#define S1_STAGE(B)                                   \
  do {                                                \
    async16(gx0, sX[B] + (wv * 64) * 8);              \
    async16(gx1, sX[B] + (512 + wv * 64) * 8);        \
    async16(gw1, sW1[B] + (wv * 64) * 8);             \
    async16(gw2, sW2[B] + (wv * 64) * 8);             \
    gx0 += 32; gx1 += 32; gw1 += 32; gw2 += 32;       \
  } while (0)

  // prologue: stage K0,K1,K2 (12 loads in flight)
  S1_STAGE(0); S1_STAGE(1); S1_STAGE(2);
  VM_WAIT(8);  // K0 landed
  S_BARRIER;
  CFENCE;

  const int NT = DIM / 32;  // 32
  for (int t = 0; t < NT; t++) {
    const int cur = t & 3;
    bf16x8 bx[8], a1[2], a2[2];
    {
      const unsigned short* xs = sX[cur];
      const unsigned short* w1s = sW1[cur];
      const unsigned short* w2s = sW2[cur];
      // W frags first so the first MFMAs' operands land earliest
#pragma unroll
      for (int j2 = 0; j2 < 2; j2++) {
        a1[j2] = *(const bf16x8*)(w1s + (wc * 32 + j2 * 16 + l15) * 32 + pch);
        a2[j2] = *(const bf16x8*)(w2s + (wc * 32 + j2 * 16 + l15) * 32 + pch);
      }
#pragma unroll
      for (int i = 0; i < 8; i++)
        bx[i] = *(const bf16x8*)(xs + (wr * 128 + i * 16 + l15) * 32 + pch);
    }
    if (t < NT - 3) {
      const int nb = (t + 3) & 3;
      S1_STAGE(nb);
    }
    // de-pinned: compiler interleaves lgkmcnt(N) waits with MFMA issue
    __builtin_amdgcn_s_setprio(1);
#pragma unroll
    for (int i = 0; i < 8; i++) {
      ah[i][0] = __builtin_amdgcn_mfma_f32_16x16x32_bf16(a1[0], bx[i], ah[i][0], 0, 0, 0);
      ag[i][0] = __builtin_amdgcn_mfma_f32_16x16x32_bf16(a2[0], bx[i], ag[i][0], 0, 0, 0);
      ah[i][1] = __builtin_amdgcn_mfma_f32_16x16x32_bf16(a1[1], bx[i], ah[i][1], 0, 0, 0);
      ag[i][1] = __builtin_amdgcn_mfma_f32_16x16x32_bf16(a2[1], bx[i], ag[i][1], 0, 0, 0);
    }
    __builtin_amdgcn_s_setprio(0);
    LGKM0;  // all ds_reads of buf[cur] done before it can be re-staged
    __builtin_amdgcn_sched_barrier(0);  // pin MFMAs from sinking past barrier
    if (t < NT - 3) VM_WAIT(8);
    else if (t == NT - 3) VM_WAIT(4);
    else if (t == NT - 2) VM_WAIT(0);
    CFENCE;
    S_BARRIER;
  }
#undef S1_STAGE

  // epilogue: out[token][hcol..hcol+3] = (h+b1) * silu(g+b2), ushort4 stores
  f32x4 b1v[2], b2v[2];
#pragma unroll
  for (int j2 = 0; j2 < 2; j2++) {
    const int hc = h0 + wc * 32 + j2 * 16 + q * 4;
    b1v[j2] = *(const f32x4*)(b1 + e * HID + hc);
    b2v[j2] = *(const f32x4*)(b2 + e * HID + hc);
  }
#pragma unroll
  for (int i = 0; i < 8; i++) {
    const int trow = wr * 128 + i * 16 + l15;
    if (trow < rows) {
      const size_t gp = (size_t)(off + ytile * 256 + trow) * HID;
#pragma unroll
      for (int j2 = 0; j2 < 2; j2++) {
        const int hc = h0 + wc * 32 + j2 * 16 + q * 4;
        ushort4 o;
        {
          const float hh = ah[i][j2][0] + b1v[j2][0];
          const float gg = ag[i][j2][0] + b2v[j2][0];
          o.x = f2bf(hh * (gg / (1.f + __expf(-gg))));
        }
        {
          const float hh = ah[i][j2][1] + b1v[j2][1];
          const float gg = ag[i][j2][1] + b2v[j2][1];
          o.y = f2bf(hh * (gg / (1.f + __expf(-gg))));
        }
        {
          const float hh = ah[i][j2][2] + b1v[j2][2];
          const float gg = ag[i][j2][2] + b2v[j2][2];
          o.z = f2bf(hh * (gg / (1.f + __expf(-gg))));
        }
        {
          const float hh = ah[i][j2][3] + b1v[j2][3];
          const float gg = ag[i][j2][3] + b2v[j2][3];
          o.w = f2bf(hh * (gg / (1.f + __expf(-gg))));
        }
        *(ushort4*)(act + gp + hc) = o;
      }
    }
  }
}

// ---------------------------------------------------------------------------
// stage2 (store path): pair_out[pr] = (act @ W3 + b3) * wt  (bf16)
// 1-D grid 2048, block 512, expert-pinned XCD swizzle, ytile-fastest order.
// 256x128 tile, BK=32, depth-4 counted pipeline, vmcnt 6/3/0. K=HID.
// ---------------------------------------------------------------------------
__global__ __launch_bounds__(512) void stage2s_kernel(
    const unsigned short* __restrict__ act, const unsigned short* __restrict__ w3bt,
    const float* __restrict__ b3, const float* __restrict__ pair_w,
    const int* __restrict__ ctrl, unsigned short* __restrict__ pair_out) {
  const int hbid = blockIdx.x;
  const int lid = ((hbid & 7) << 8) + (hbid >> 3);  // expert-pinned per XCD
  const int e = lid >> 8;
  const int s = lid & 255;
  const int ytile = s & 31;          // fastest: resident blocks share d0-panel
  const int d0 = (s >> 5) * 128;

  const int cnt = ctrl[e];
  if (ytile * 256 >= cnt) return;
  const int off = ctrl[8 + e];
  const int rows = min(256, cnt - ytile * 256);
  const int rbase = off + ytile * 256;

  __shared__ unsigned short sA[4][256 * 32];  // 64 KB
  __shared__ unsigned short sW[4][128 * 32];  // 32 KB

  const int tid = threadIdx.x;
  const int wv = tid >> 6, lane = tid & 63;
  const int cl = ((tid & 3) ^ ((tid >> 3) & 3)) * 8;

  const unsigned short* w3p = w3bt + (size_t)e * DIM * HID + (size_t)d0 * HID;
  const unsigned short* ga0 =
      act + (size_t)(rbase + min(tid >> 2, rows - 1)) * HID + cl;
  const unsigned short* ga1 =
      act + (size_t)(rbase + min(128 + (tid >> 2), rows - 1)) * HID + cl;
  const unsigned short* gw = w3p + (size_t)(tid >> 2) * HID + cl;

  f32x4 acc[8][2];
#pragma unroll
  for (int i = 0; i < 8; i++)
#pragma unroll
    for (int jj = 0; jj < 2; jj++) acc[i][jj] = (f32x4){0.f, 0.f, 0.f, 0.f};

  const int wr = wv >> 2, wc = wv & 3;
  const int l15 = lane & 15, q = lane >> 4;
  const int pch = (q ^ ((l15 >> 1) & 3)) * 8;

#define S2_STAGE(B)                                   \
  do {                                                \
    async16(ga0, sA[B] + (wv * 64) * 8);              \
    async16(ga1, sA[B] + (512 + wv * 64) * 8);        \
    async16(gw, sW[B] + (wv * 64) * 8);               \
    ga0 += 32; ga1 += 32; gw += 32;                   \
  } while (0)

  S2_STAGE(0); S2_STAGE(1); S2_STAGE(2);  // 9 loads in flight
  VM_WAIT(6);  // K0 landed
  S_BARRIER;
  CFENCE;

  const int NT = HID / 32;  // 64
  for (int t = 0; t < NT; t++) {
    const int cur = t & 3;
    bf16x8 af[8], bf[2];
    {
      const unsigned short* as = sA[cur];
      const unsigned short* ws = sW[cur];
#pragma unroll
      for (int jj = 0; jj < 2; jj++)
        bf[jj] = *(const bf16x8*)(ws + (wc * 32 + jj * 16 + l15) * 32 + pch);
#pragma unroll
      for (int i = 0; i < 8; i++)
        af[i] = *(const bf16x8*)(as + (wr * 128 + i * 16 + l15) * 32 + pch);
    }
    if (t < NT - 3) {
      const int nb = (t + 3) & 3;
      S2_STAGE(nb);
    }
    __builtin_amdgcn_s_setprio(1);
#pragma unroll
    for (int i = 0; i < 8; i++)
#pragma unroll
      for (int jj = 0; jj < 2; jj++)
        acc[i][jj] =
            __builtin_amdgcn_mfma_f32_16x16x32_bf16(af[i], bf[jj], acc[i][jj], 0, 0, 0);
    __builtin_amdgcn_s_setprio(0);
    LGKM0;
    __builtin_amdgcn_sched_barrier(0);
    if (t < NT - 3) VM_WAIT(6);
    else if (t == NT - 3) VM_WAIT(3);
    else if (t == NT - 2) VM_WAIT(0);
    CFENCE;
    S_BARRIER;
  }
#undef S2_STAGE

#pragma unroll
  for (int i = 0; i < 8; i++)
#pragma unroll
    for (int rg = 0; rg < 4; rg++) {
      const int row = wr * 128 + i * 16 + q * 4 + rg;
      if (row < rows) {
        const int pr = rbase + row;
        const float wt = pair_w[pr];
#pragma unroll
        for (int jj = 0; jj < 2; jj++) {
          const int dcol = d0 + wc * 32 + jj * 16 + l15;
          pair_out[(size_t)pr * DIM + dcol] = f2bf((acc[i][jj][rg] + b3[e * DIM + dcol]) * wt);
        }
      }
    }
}

// ---------------------------------------------------------------------------
// stage2 (atomic fallback): out[tok] += (act @ W3 + b3) * wt
// ---------------------------------------------------------------------------
__global__ __launch_bounds__(512) void stage2a_kernel(
    const unsigned short* __restrict__ act, const unsigned short* __restrict__ w3bt,
    const float* __restrict__ b3, const int* __restrict__ tok_list,
    const float* __restrict__ pair_w, const int* __restrict__ ctrl,
    float* __restrict__ out) {
  const int hbid = blockIdx.x;
  const int lid = ((hbid & 7) << 8) + (hbid >> 3);
  const int e = lid >> 8;
  const int s = lid & 255;
  const int ytile = s & 31;
  const int d0 = (s >> 5) * 128;

  const int cnt = ctrl[e];
  if (ytile * 256 >= cnt) return;
  const int off = ctrl[8 + e];
  const int rows = min(256, cnt - ytile * 256);
  const int rbase = off + ytile * 256;

  __shared__ unsigned short sA[4][256 * 32];
  __shared__ unsigned short sW[4][128 * 32];

  const int tid = threadIdx.x;
  const int wv = tid >> 6, lane = tid & 63;
  const int cl = ((tid & 3) ^ ((tid >> 3) & 3)) * 8;

  const unsigned short* w3p = w3bt + (size_t)e * DIM * HID + (size_t)d0 * HID;
  const unsigned short* ga0 =
      act + (size_t)(rbase + min(tid >> 2, rows - 1)) * HID + cl;
  const unsigned short* ga1 =
      act + (size_t)(rbase + min(128 + (tid >> 2), rows - 1)) * HID + cl;
  const unsigned short* gw = w3p + (size_t)(tid >> 2) * HID + cl;

  f32x4 acc[8][2];
#pragma unroll
  for (int i = 0; i < 8; i++)
#pragma unroll
    for (int jj = 0; jj < 2; jj++) acc[i][jj] = (f32x4){0.f, 0.f, 0.f, 0.f};

  const int wr = wv >> 2, wc = wv & 3;
  const int l15 = lane & 15, q = lane >> 4;
  const int pch = (q ^ ((l15 >> 1) & 3)) * 8;

#define S2A_STAGE(B)                                  \
  do {                                                \
    async16(ga0, sA[B] + (wv * 64) * 8);              \
    async16(ga1, sA[B] + (512 + wv * 64) * 8);        \
    async16(gw, sW[B] + (wv * 64) * 8);               \
    ga0 += 32; ga1 += 32; gw += 32;                   \
  } while (0)

  S2A_STAGE(0); S2A_STAGE(1); S2A_STAGE(2);
  VM_WAIT(6);
  S_BARRIER;
  CFENCE;

  const int NT = HID / 32;
  for (int t = 0; t < NT; t++) {
    const int cur = t & 3;
    bf16x8 af[8], bf[2];
    {
      const unsigned short* as = sA[cur];
      const unsigned short* ws = sW[cur];
#pragma unroll
      for (int jj = 0; jj < 2; jj++)
        bf[jj] = *(const bf16x8*)(ws + (wc * 32 + jj * 16 + l15) * 32 + pch);
#pragma unroll
      for (int i = 0; i < 8; i++)
        af[i] = *(const bf16x8*)(as + (wr * 128 + i * 16 + l15) * 32 + pch);
    }
    if (t < NT - 3) {
      const int nb = (t + 3) & 3;
      S2A_STAGE(nb);
    }
    __builtin_amdgcn_s_setprio(1);
#pragma unroll
    for (int i = 0; i < 8; i++)
#pragma unroll
      for (int jj = 0; jj < 2; jj++)
        acc[i][jj] =
            __builtin_amdgcn_mfma_f32_16x16x32_bf16(af[i], bf[jj], acc[i][jj], 0, 0, 0);
    __builtin_amdgcn_s_setprio(0);
    LGKM0;
    __builtin_amdgcn_sched_barrier(0);
    if (t < NT - 3) VM_WAIT(6);
    else if (t == NT - 3) VM_WAIT(3);
    else if (t == NT - 2) VM_WAIT(0);
    CFENCE;
    S_BARRIER;
  }
#undef S2A_STAGE

#pragma unroll
  for (int i = 0; i < 8; i++)
#pragma unroll
    for (int rg = 0; rg < 4; rg++) {
      const int row = wr * 128 + i * 16 + q * 4 + rg;
      if (row < rows) {
        const int pr = rbase + row;
        const int tok = tok_list[pr];
        const float wt = pair_w[pr];
#pragma unroll
        for (int jj = 0; jj < 2; jj++) {
          const int dcol = d0 + wc * 32 + jj * 16 + l15;
          atomicAdd(out + (size_t)tok * DIM + dcol, (acc[i][jj][rg] + b3[e * DIM + dcol]) * wt);
        }
      }
    }
}

// ---------------------------------------------------------------------------
// combine: out[t] = pair_out[pos(t,0)] + pair_out[pos(t,1)].
// grid NTOK/8 = 1024 blocks x 256 thr, 8 tokens per block.
// ---------------------------------------------------------------------------
__global__ __launch_bounds__(256) void combine_kernel(
    const unsigned short* __restrict__ pair_out, const int* __restrict__ pair_pos,
    float* __restrict__ out) {
  const int d = threadIdx.x * 4;
#pragma unroll
  for (int tt = 0; tt < 8; tt++) {
    const int t = blockIdx.x * 8 + tt;
    const int p0 = pair_pos[t * 2], p1 = pair_pos[t * 2 + 1];
    const ushort4 a = *(const ushort4*)(pair_out + (size_t)p0 * DIM + d);
    const ushort4 b = *(const ushort4*)(pair_out + (size_t)p1 * DIM + d);
    float4 r;
    r.x = bf2f(a.x) + bf2f(b.x);
    r.y = bf2f(a.y) + bf2f(b.y);
    r.z = bf2f(a.z) + bf2f(b.z);
    r.w = bf2f(a.w) + bf2f(b.w);
    *(float4*)(out + (size_t)t * DIM + d) = r;
  }
}

// ---------------------------------------------------------------------------
// workspace layout (bytes)
// ---------------------------------------------------------------------------
static const size_t SZ_XB  = (size_t)NTOK * DIM * 2;        // 16 MB
static const size_t SZ_W   = (size_t)NE * DIM * HID * 2;    // 32 MB each
static const size_t SZ_ACT = (size_t)NPAIR * HID * 2;       // 64 MB
static const size_t OFF_XB  = 0;
static const size_t OFF_W1  = OFF_XB + SZ_XB;
static const size_t OFF_W2  = OFF_W1 + SZ_W;
static const size_t OFF_W3  = OFF_W2 + SZ_W;
static const size_t OFF_ACT = OFF_W3 + SZ_W;
static const size_t OFF_SC  = OFF_ACT + SZ_ACT;
static const size_t OFF_RE  = OFF_SC + (size_t)NTOK * NE * 4;
static const size_t OFF_RW  = OFF_RE + (size_t)NPAIR * 4;
static const size_t OFF_TL  = OFF_RW + (size_t)NPAIR * 4;
static const size_t OFF_PW  = OFF_TL + (size_t)NPAIR * 4;
static const size_t OFF_PP  = OFF_PW + (size_t)NPAIR * 4;
static const size_t OFF_CT  = OFF_PP + (size_t)NPAIR * 4;
static const size_t WS_BASE = OFF_CT + 128;
static const size_t OFF_PO  = WS_BASE;                      // pair_out bf16, 32 MB
static const size_t WS_FULL = OFF_PO + (size_t)NPAIR * DIM * 2;

extern "C" void kernel_launch(void* const* d_in, const int* in_sizes, int n_in,
                              void* d_out, int out_size, void* d_ws, size_t ws_size,
                              hipStream_t stream) {
  const float* x      = (const float*)d_in[0];
  const float* gate_w = (const float*)d_in[1];
  const float* gate_b = (const float*)d_in[2];
  const float* w1     = (const float*)d_in[3];
  const float* b1     = (const float*)d_in[4];
  const float* w2     = (const float*)d_in[5];
  const float* b2     = (const float*)d_in[6];
  const float* w3     = (const float*)d_in[7];
  const float* b3     = (const float*)d_in[8];
  float* out = (float*)d_out;

  if (ws_size < WS_BASE) {
    fprintf(stderr, "kernel_launch: ws_size %zu < needed %zu\n", ws_size, WS_BASE);
    return;
  }
  const bool store_path = (ws_size >= WS_FULL);

  char* ws = (char*)d_ws;
  unsigned short* xb   = (unsigned short*)(ws + OFF_XB);
  unsigned short* w1bt = (unsigned short*)(ws + OFF_W1);
  unsigned short* w2bt = (unsigned short*)(ws + OFF_W2);
  unsigned short* w3bt = (unsigned short*)(ws + OFF_W3);
  unsigned short* act  = (unsigned short*)(ws + OFF_ACT);
  float* scores        = (float*)(ws + OFF_SC);
  int* route_e         = (int*)(ws + OFF_RE);
  float* route_w       = (float*)(ws + OFF_RW);
  int* tok_list        = (int*)(ws + OFF_TL);
  float* pair_w        = (float*)(ws + OFF_PW);
  int* pair_pos        = (int*)(ws + OFF_PP);
  int* ctrl            = (int*)(ws + OFF_CT);
  unsigned short* pout = (unsigned short*)(ws + OFF_PO);

  if (!store_path)
    hipMemsetAsync(d_out, 0, (size_t)out_size * sizeof(float), stream);

  prepgate_kernel<<<14336, 256, 0, stream>>>(w1, w2, w3, w1bt, w2bt, w3bt,
                                             x, gate_w, gate_b, xb, scores,
                                             route_e, route_w);
  finalize_kernel<<<1, 1024, 0, stream>>>(scores, route_e, ctrl, out + (out_size - 1));
  scatter_kernel<<<32, 256, 0, stream>>>(route_e, route_w, ctrl, tok_list, pair_w,
                                         pair_pos);
  stage1_kernel<<<4096, 512, 0, stream>>>(xb, w1bt, w2bt, b1, b2, tok_list, ctrl, act);
  if (store_path) {
    stage2s_kernel<<<2048, 512, 0, stream>>>(act, w3bt, b3, pair_w, ctrl, pout);
    combine_kernel<<<1024, 256, 0, stream>>>(pout, pair_pos, out);
  } else {
    stage2a_kernel<<<2048, 512, 0, stream>>>(act, w3bt, b3, tok_list, pair_w,
                                             ctrl, out);
  }
}

// Round 13
// 542.914 us; speedup vs baseline: 1.1083x; 1.1083x over previous
//
#include <hip/hip_runtime.h>
#include <cstdio>

#define NTOK 8192
#define DIM 1024
#define HID 2048
#define NE 8
#define NPAIR (NTOK * 2)

typedef __attribute__((ext_vector_type(8))) short bf16x8;
typedef __attribute__((ext_vector_type(4))) float f32x4;

typedef const __attribute__((address_space(1))) void* gas_ptr;
typedef __attribute__((address_space(3))) void* las_ptr;

__device__ __forceinline__ void async16(const void* g, void* s) {
  // direct global->LDS, 16B per lane; LDS dest = wave-uniform base + lane*16
  __builtin_amdgcn_global_load_lds((gas_ptr)g, (las_ptr)s, 16, 0, 0);
}

__device__ __forceinline__ unsigned short f2bf(float f) {
  unsigned int u = __float_as_uint(f);
  u = (u + 0x7fff + ((u >> 16) & 1)) >> 16;  // RNE
  return (unsigned short)u;
}

__device__ __forceinline__ float bf2f(unsigned short u) {
  return __uint_as_float((unsigned int)u << 16);
}

// r18: REVERT to session optimum = r11 config (measured 544.0 us).
// Lever ledger (stage1 us): schedule pinned/de-pinned/2-phase = 198/183/202;
// depth-2 2blk/CU = 206; balanced-XCD = 233 (+122MB FETCH); ytile-fastest =
// 233 (X-thrash worse than W-thrash). Every deviation from this config
// measured and refuted; this is the empirical argmax.
// Structure: stage1 de-pinned depth-4 counted-vmcnt (vmcnt 8/4/0, 4 buf),
// expert-pinned XCD swizzle, h0-minor order; stage2 BN=256 acc[8][4];
// combine 1 token/block; prepgate fused; scatter LDS-hist.

#define S_BARRIER __builtin_amdgcn_s_barrier()
#define VM_WAIT(N) asm volatile("s_waitcnt vmcnt(" #N ")" ::: "memory")
#define LGKM0 asm volatile("s_waitcnt lgkmcnt(0)" ::: "memory")
#define CFENCE asm volatile("" ::: "memory")

// ---------------------------------------------------------------------------
// prepgate: fused prep (blocks 0..12287) + gate (blocks 12288..14335).
// ---------------------------------------------------------------------------
__global__ __launch_bounds__(256) void prepgate_kernel(
    const float* __restrict__ w1, const float* __restrict__ w2,
    const float* __restrict__ w3, unsigned short* __restrict__ w1bt,
    unsigned short* __restrict__ w2bt, unsigned short* __restrict__ w3bt,
    const float* __restrict__ x, const float* __restrict__ gw,
    const float* __restrict__ gb, unsigned short* __restrict__ xb,
    float* __restrict__ scores, int* __restrict__ route_e,
    float* __restrict__ route_w) {
  __shared__ float smem[NE * DIM];  // 32 KB union: prep tT[64][65], gate sgwT
  const int bx = blockIdx.x;
  const int tid = threadIdx.x;

  if (bx < 12288) {
    // ---- prep path ----
    float (*tT)[65] = reinterpret_cast<float(*)[65]>(smem);
    const int z = bx >> 9;     // 0..23
    const int bxx = bx & 511;
    const int m = z >> 3, e = z & 7;
    int R, C;
    const float* in;
    unsigned short* outp;
    if (m == 0)      { R = DIM; C = HID; in = w1; outp = w1bt; }
    else if (m == 1) { R = DIM; C = HID; in = w2; outp = w2bt; }
    else             { R = HID; C = DIM; in = w3; outp = w3bt; }
    in += (size_t)e * DIM * HID;
    outp += (size_t)e * DIM * HID;

    const int tilesx = C >> 6;
    const int c0 = (bxx % tilesx) * 64;
    const int r0 = (bxx / tilesx) * 64;

    const int cq = tid & 15;   // float4-col index
    const int rr = tid >> 4;   // 0..15
#pragma unroll
    for (int p = 0; p < 4; p++) {
      const int r = rr + p * 16;
      const float4 v = *(const float4*)(in + (size_t)(r0 + r) * C + c0 + cq * 4);
      tT[cq * 4 + 0][r] = v.x;
      tT[cq * 4 + 1][r] = v.y;
      tT[cq * 4 + 2][r] = v.z;
      tT[cq * 4 + 3][r] = v.w;
    }
    __syncthreads();
    // store: thread handles 8 consecutive r-cols of one output row -> 16B
    const int cc8 = tid & 7;   // 8-col group
    const int rr2 = tid >> 3;  // 0..31
#pragma unroll
    for (int p = 0; p < 2; p++) {
      const int cc = rr2 + p * 32;  // output row (= original col)
      bf16x8 o;
#pragma unroll
      for (int k = 0; k < 8; k++) o[k] = (short)f2bf(tT[cc][cc8 * 8 + k]);
      *(bf16x8*)(outp + (size_t)(c0 + cc) * R + r0 + cc8 * 8) = o;
    }
    return;
  }

  // ---- gate path ----
  float (*sgwT)[DIM] = reinterpret_cast<float(*)[DIM]>(smem);  // [NE][DIM]
  const int g = bx - 12288;
#pragma unroll
  for (int i = 0; i < 8; i++) {
    const int j = i * 256 + tid;               // float4 index into gw[DIM][NE]
    const float4 v = ((const float4*)gw)[j];
    const int d = j >> 1, e0 = (j & 1) * 4;    // 2-way bank alias on store: free
    sgwT[e0 + 0][d] = v.x; sgwT[e0 + 1][d] = v.y;
    sgwT[e0 + 2][d] = v.z; sgwT[e0 + 3][d] = v.w;
  }
  __syncthreads();

  const int wv = tid >> 6, lane = tid & 63;
  const int t = g * 4 + wv;
  float acc[NE] = {0.f, 0.f, 0.f, 0.f, 0.f, 0.f, 0.f, 0.f};
  const float4* x4 = (const float4*)(x + (size_t)t * DIM);
#pragma unroll
  for (int i = 0; i < 4; i++) {
    const float4 xv = x4[i * 64 + lane];
    const int d4 = i * 64 + lane;
    ushort4 xbv;
    xbv.x = f2bf(xv.x); xbv.y = f2bf(xv.y);
    xbv.z = f2bf(xv.z); xbv.w = f2bf(xv.w);
    *(ushort4*)(xb + (size_t)t * DIM + d4 * 4) = xbv;
#pragma unroll
    for (int e = 0; e < NE; e++) {
      const float4 wv4 = *(const float4*)&sgwT[e][d4 * 4];  // ds_read_b128
      acc[e] += xv.x * wv4.x + xv.y * wv4.y + xv.z * wv4.z + xv.w * wv4.w;
    }
  }
#pragma unroll
  for (int e = 0; e < NE; e++)
#pragma unroll
    for (int s = 32; s; s >>= 1) acc[e] += __shfl_xor(acc[e], s, 64);

  if (lane == 0) {
    float l[NE], m = -1e30f;
#pragma unroll
    for (int e = 0; e < NE; e++) { l[e] = acc[e] + gb[e]; m = fmaxf(m, l[e]); }
    float p[NE], sum = 0.f;
#pragma unroll
    for (int e = 0; e < NE; e++) { p[e] = __expf(l[e] - m); sum += p[e]; }
    const float inv = 1.f / sum;
    float s[NE];
#pragma unroll
    for (int e = 0; e < NE; e++) { s[e] = p[e] * inv; scores[t * NE + e] = s[e]; }
    int i1 = 0;
    for (int e = 1; e < NE; e++) if (s[e] > s[i1]) i1 = e;
    int i2 = -1;
    for (int e = 0; e < NE; e++) {
      if (e == i1) continue;
      if (i2 < 0 || s[e] > s[i2]) i2 = e;
    }
    route_e[t * 2] = i1; route_e[t * 2 + 1] = i2;
    route_w[t * 2] = s[i1]; route_w[t * 2 + 1] = s[i2];
  }
}

// ---------------------------------------------------------------------------
// finalize: usage -> lb_loss (d_out tail); counts via route_e histogram;
// prefix offsets; cursors. Writes every ctrl field (no memset needed).
// ---------------------------------------------------------------------------
__global__ void finalize_kernel(const float* __restrict__ scores,
                                const int* __restrict__ route_e,
                                int* __restrict__ ctrl,
                                float* __restrict__ out_lb) {
  __shared__ float red[1024];
  __shared__ int hist[NE];
  const int tid = threadIdx.x;
  if (tid < NE) hist[tid] = 0;
  const int e = tid & 7, row = tid >> 3;
  float s = 0.f;
  for (int i = 0; i < 64; i++) s += scores[(size_t)(row + i * 128) * NE + e];
  red[tid] = s;
  __syncthreads();  // hist zero + red visible
#pragma unroll
  for (int i = 0; i < 16; i++)
    atomicAdd(&hist[route_e[i * 1024 + tid]], 1);
  for (int st = 512; st >= 8; st >>= 1) {
    __syncthreads();
    if (tid < st) red[tid] += red[tid + st];
  }
  __syncthreads();
  if (tid == 0) {
    float lb = 0.f;
    for (int ee = 0; ee < NE; ee++) {
      const float u = red[ee] * (1.f / 8192.f);
      lb -= u * __logf(u + 1e-9f);
    }
    *out_lb = lb;
    int o = 0;
    for (int ee = 0; ee < NE; ee++) {
      ctrl[ee] = hist[ee];    // counts
      ctrl[8 + ee] = o;       // offsets
      ctrl[17 + ee] = o;      // cursors
      o += hist[ee];
    }
    ctrl[16] = o;
  }
}

// ---------------------------------------------------------------------------
// scatter: per-block LDS histogram -> 8 global atomics per block.
// ---------------------------------------------------------------------------
__global__ __launch_bounds__(256) void scatter_kernel(
    const int* __restrict__ route_e, const float* __restrict__ route_w,
    int* __restrict__ ctrl, int* __restrict__ tok_list,
    float* __restrict__ pair_w, int* __restrict__ pair_pos) {
  __shared__ int lh[NE];
  __shared__ int lbase[NE];
  const int tid = threadIdx.x;
  const int t = blockIdx.x * 256 + tid;
  if (tid < NE) lh[tid] = 0;
  __syncthreads();
  const int e0 = route_e[t * 2], e1 = route_e[t * 2 + 1];
  const int p0 = atomicAdd(&lh[e0], 1);
  const int p1 = atomicAdd(&lh[e1], 1);  // e1 != e0 (top-2 distinct)
  __syncthreads();
  if (tid < NE) lbase[tid] = atomicAdd(&ctrl[17 + tid], lh[tid]);
  __syncthreads();
  const int q0 = lbase[e0] + p0;
  const int q1 = lbase[e1] + p1;
  tok_list[q0] = t;
  pair_w[q0] = route_w[t * 2] * 0.70710678118654752f;
  pair_pos[t * 2] = q0;
  tok_list[q1] = t;
  pair_w[q1] = route_w[t * 2 + 1] * 0.70710678118654752f;
  pair_pos[t * 2 + 1] = q1;
}

// ---------------------------------------------------------------------------
// stage1 (FUSED): act = (X@W1+b1) * silu(X@W2+b2) for routed rows (bf16)
// 1-D grid 4096, block 512, expert-pinned XCD swizzle (512 blocks = 1
// expert/XCD, h0-minor). M=256 x N=128 tile, BK=32, depth-4 counted-vmcnt
// pipeline, de-pinned MFMA scheduling. Measured 183us / 168MB FETCH.
// ---------------------------------------------------------------------------
__global__ __launch_bounds__(512) void stage1_kernel(
    const unsigned short* __restrict__ xb, const unsigned short* __restrict__ w1bt,
    const unsigned short* __restrict__ w2bt, const float* __restrict__ b1,
    const float* __restrict__ b2, const int* __restrict__ tok_list,
    const int* __restrict__ ctrl, unsigned short* __restrict__ act) {
  const int hbid = blockIdx.x;
  const int lid = ((hbid & 7) << 9) + (hbid >> 3);  // expert-pinned per XCD
  const int e = lid >> 9;
  const int ytile = (lid >> 4) & 31;
  const int h0 = (lid & 15) * 128;

  const int cnt = ctrl[e];
  if (ytile * 256 >= cnt) return;
  const int off = ctrl[8 + e];
  const int rows = min(256, cnt - ytile * 256);

  __shared__ unsigned short sX[4][256 * 32];   // 64 KB
  __shared__ unsigned short sW1[4][128 * 32];  // 32 KB
  __shared__ unsigned short sW2[4][128 * 32];  // 32 KB

  const int tid = threadIdx.x;
  const int wv = tid >> 6, lane = tid & 63;
  const int cl = ((tid & 3) ^ ((tid >> 3) & 3)) * 8;  // swizzled k-offset

  const unsigned short* w1p = w1bt + (size_t)e * HID * DIM + (size_t)h0 * DIM;
  const unsigned short* w2p = w2bt + (size_t)e * HID * DIM + (size_t)h0 * DIM;
  const unsigned short* gx0 =
      xb + (size_t)tok_list[off + ytile * 256 + min(tid >> 2, rows - 1)] * DIM + cl;
  const unsigned short* gx1 =
      xb + (size_t)tok_list[off + ytile * 256 + min(128 + (tid >> 2), rows - 1)] * DIM + cl;
  const unsigned short* gw1 = w1p + (size_t)(tid >> 2) * DIM + cl;
  const unsigned short* gw2 = w2p + (size_t)(tid >> 2) * DIM + cl;

  f32x4 ah[8][2], ag[8][2];
#pragma unroll
  for (int i = 0; i < 8; i++)
#pragma unroll
    for (int j2 = 0; j2 < 2; j2++) {
      ah[i][j2] = (f32x4){0.f, 0.f, 0.f, 0.f};
      ag[i][j2] = (f32x4){0.f, 0.f, 0.f, 0.f};
    }

  const int wr = wv >> 2, wc = wv & 3;
  const int l15 = lane & 15, q = lane >> 4;
  const int pch = (q ^ ((l15 >> 1) & 3)) * 8;

#define S1_STAGE(B)                                   \
  do {                                                \
    async16(gx0, sX[B] + (wv * 64) * 8);              \
    async16(gx1, sX[B] + (512 + wv * 64) * 8);        \
    async16(gw1, sW1[B] + (wv * 64) * 8);             \
    async16(gw2, sW2[B] + (wv * 64) * 8);             \
    gx0 += 32; gx1 += 32; gw1 += 32; gw2 += 32;       \
  } while (0)

  // prologue: stage K0,K1,K2 (12 loads in flight)
  S1_STAGE(0); S1_STAGE(1); S1_STAGE(2);
  VM_WAIT(8);  // K0 landed
  S_BARRIER;
  CFENCE;

  const int NT = DIM / 32;  // 32
  for (int t = 0; t < NT; t++) {
    const int cur = t & 3;
    bf16x8 bx[8], a1[2], a2[2];
    {
      const unsigned short* xs = sX[cur];
      const unsigned short* w1s = sW1[cur];
      const unsigned short* w2s = sW2[cur];
      // W frags first so the first MFMAs' operands land earliest
#pragma unroll
      for (int j2 = 0; j2 < 2; j2++) {
        a1[j2] = *(const bf16x8*)(w1s + (wc * 32 + j2 * 16 + l15) * 32 + pch);
        a2[j2] = *(const bf16x8*)(w2s + (wc * 32 + j2 * 16 + l15) * 32 + pch);
      }
#pragma unroll
      for (int i = 0; i < 8; i++)
        bx[i] = *(const bf16x8*)(xs + (wr * 128 + i * 16 + l15) * 32 + pch);
    }
    if (t < NT - 3) {
      const int nb = (t + 3) & 3;
      S1_STAGE(nb);
    }
    // de-pinned: compiler interleaves lgkmcnt(N) waits with MFMA issue
    __builtin_amdgcn_s_setprio(1);
#pragma unroll
    for (int i = 0; i < 8; i++) {
      ah[i][0] = __builtin_amdgcn_mfma_f32_16x16x32_bf16(a1[0], bx[i], ah[i][0], 0, 0, 0);
      ag[i][0] = __builtin_amdgcn_mfma_f32_16x16x32_bf16(a2[0], bx[i], ag[i][0], 0, 0, 0);
      ah[i][1] = __builtin_amdgcn_mfma_f32_16x16x32_bf16(a1[1], bx[i], ah[i][1], 0, 0, 0);
      ag[i][1] = __builtin_amdgcn_mfma_f32_16x16x32_bf16(a2[1], bx[i], ag[i][1], 0, 0, 0);
    }
    __builtin_amdgcn_s_setprio(0);
    LGKM0;  // all ds_reads of buf[cur] done before it can be re-staged
    __builtin_amdgcn_sched_barrier(0);  // pin MFMAs from sinking past barrier
    if (t < NT - 3) VM_WAIT(8);
    else if (t == NT - 3) VM_WAIT(4);
    else if (t == NT - 2) VM_WAIT(0);
    CFENCE;
    S_BARRIER;
  }
#undef S1_STAGE

  // epilogue: out[token][hcol..hcol+3] = (h+b1) * silu(g+b2), ushort4 stores
  f32x4 b1v[2], b2v[2];
#pragma unroll
  for (int j2 = 0; j2 < 2; j2++) {
    const int hc = h0 + wc * 32 + j2 * 16 + q * 4;
    b1v[j2] = *(const f32x4*)(b1 + e * HID + hc);
    b2v[j2] = *(const f32x4*)(b2 + e * HID + hc);
  }
#pragma unroll
  for (int i = 0; i < 8; i++) {
    const int trow = wr * 128 + i * 16 + l15;
    if (trow < rows) {
      const size_t gp = (size_t)(off + ytile * 256 + trow) * HID;
#pragma unroll
      for (int j2 = 0; j2 < 2; j2++) {
        const int hc = h0 + wc * 32 + j2 * 16 + q * 4;
        ushort4 o;
        {
          const float hh = ah[i][j2][0] + b1v[j2][0];
          const float gg = ag[i][j2][0] + b2v[j2][0];
          o.x = f2bf(hh * (gg / (1.f + __expf(-gg))));
        }
        {
          const float hh = ah[i][j2][1] + b1v[j2][1];
          const float gg = ag[i][j2][1] + b2v[j2][1];
          o.y = f2bf(hh * (gg / (1.f + __expf(-gg))));
        }
        {
          const float hh = ah[i][j2][2] + b1v[j2][2];
          const float gg = ag[i][j2][2] + b2v[j2][2];
          o.z = f2bf(hh * (gg / (1.f + __expf(-gg))));
        }
        {
          const float hh = ah[i][j2][3] + b1v[j2][3];
          const float gg = ag[i][j2][3] + b2v[j2][3];
          o.w = f2bf(hh * (gg / (1.f + __expf(-gg))));
        }
        *(ushort4*)(act + gp + hc) = o;
      }
    }
  }
}

// ---------------------------------------------------------------------------
// stage2 (store path): pair_out[pr] = (act @ W3 + b3) * wt  (bf16)
// 1-D grid 1024, block 512, expert-pinned XCD swizzle. 256x256 tile, BK=32,
// depth-4 counted pipeline, de-pinned, K=HID. (r11 config)
// ---------------------------------------------------------------------------
__global__ __launch_bounds__(512) void stage2s_kernel(
    const unsigned short* __restrict__ act, const unsigned short* __restrict__ w3bt,
    const float* __restrict__ b3, const float* __restrict__ pair_w,
    const int* __restrict__ ctrl, unsigned short* __restrict__ pair_out) {
  const int hbid = blockIdx.x;
  const int lid = ((hbid & 7) << 7) + (hbid >> 3);  // expert-pinned per XCD
  const int e = lid >> 7;
  const int ytile = (lid >> 2) & 31;
  const int d0 = (lid & 3) * 256;

  const int cnt = ctrl[e];
  if (ytile * 256 >= cnt) return;
  const int off = ctrl[8 + e];
  const int rows = min(256, cnt - ytile * 256);
  const int rbase = off + ytile * 256;

  __shared__ unsigned short sA[4][256 * 32];  // 64 KB
  __shared__ unsigned short sW[4][256 * 32];  // 64 KB

  const int tid = threadIdx.x;
  const int wv = tid >> 6, lane = tid & 63;
  const int cl = ((tid & 3) ^ ((tid >> 3) & 3)) * 8;

  const unsigned short* w3p = w3bt + (size_t)e * DIM * HID + (size_t)d0 * HID;
  const unsigned short* ga0 =
      act + (size_t)(rbase + min(tid >> 2, rows - 1)) * HID + cl;
  const unsigned short* ga1 =
      act + (size_t)(rbase + min(128 + (tid >> 2), rows - 1)) * HID + cl;
  const unsigned short* gw0 = w3p + (size_t)(tid >> 2) * HID + cl;
  const unsigned short* gw1 = w3p + (size_t)(128 + (tid >> 2)) * HID + cl;

  f32x4 acc[8][4];
#pragma unroll
  for (int i = 0; i < 8; i++)
#pragma unroll
    for (int jj = 0; jj < 4; jj++) acc[i][jj] = (f32x4){0.f, 0.f, 0.f, 0.f};

  const int wr = wv >> 2, wc = wv & 3;
  const int l15 = lane & 15, q = lane >> 4;
  const int pch = (q ^ ((l15 >> 1) & 3)) * 8;

#define S2_STAGE(B)                                   \
  do {                                                \
    async16(ga0, sA[B] + (wv * 64) * 8);              \
    async16(ga1, sA[B] + (512 + wv * 64) * 8);        \
    async16(gw0, sW[B] + (wv * 64) * 8);              \
    async16(gw1, sW[B] + (512 + wv * 64) * 8);        \
    ga0 += 32; ga1 += 32; gw0 += 32; gw1 += 32;       \
  } while (0)

  S2_STAGE(0); S2_STAGE(1); S2_STAGE(2);
  VM_WAIT(8);
  S_BARRIER;
  CFENCE;

  const int NT = HID / 32;  // 64
  for (int t = 0; t < NT; t++) {
    const int cur = t & 3;
    bf16x8 af[8], bf[4];
    {
      const unsigned short* as = sA[cur];
      const unsigned short* ws = sW[cur];
#pragma unroll
      for (int jj = 0; jj < 4; jj++)
        bf[jj] = *(const bf16x8*)(ws + (wc * 64 + jj * 16 + l15) * 32 + pch);
#pragma unroll
      for (int i = 0; i < 8; i++)
        af[i] = *(const bf16x8*)(as + (wr * 128 + i * 16 + l15) * 32 + pch);
    }
    if (t < NT - 3) {
      const int nb = (t + 3) & 3;
      S2_STAGE(nb);
    }
    __builtin_amdgcn_s_setprio(1);
#pragma unroll
    for (int i = 0; i < 8; i++)
#pragma unroll
      for (int jj = 0; jj < 4; jj++)
        acc[i][jj] =
            __builtin_amdgcn_mfma_f32_16x16x32_bf16(af[i], bf[jj], acc[i][jj], 0, 0, 0);
    __builtin_amdgcn_s_setprio(0);
    LGKM0;
    __builtin_amdgcn_sched_barrier(0);
    if (t < NT - 3) VM_WAIT(8);
    else if (t == NT - 3) VM_WAIT(4);
    else if (t == NT - 2) VM_WAIT(0);
    CFENCE;
    S_BARRIER;
  }
#undef S2_STAGE

#pragma unroll
  for (int i = 0; i < 8; i++)
#pragma unroll
    for (int rg = 0; rg < 4; rg++) {
      const int row = wr * 128 + i * 16 + q * 4 + rg;
      if (row < rows) {
        const int pr = rbase + row;
        const float wt = pair_w[pr];
#pragma unroll
        for (int jj = 0; jj < 4; jj++) {
          const int dcol = d0 + wc * 64 + jj * 16 + l15;
          pair_out[(size_t)pr * DIM + dcol] = f2bf((acc[i][jj][rg] + b3[e * DIM + dcol]) * wt);
        }
      }
    }
}

// ---------------------------------------------------------------------------
// stage2 (atomic fallback): out[tok] += (act @ W3 + b3) * wt
// ---------------------------------------------------------------------------
__global__ __launch_bounds__(512) void stage2a_kernel(
    const unsigned short* __restrict__ act, const unsigned short* __restrict__ w3bt,
    const float* __restrict__ b3, const int* __restrict__ tok_list,
    const float* __restrict__ pair_w, const int* __restrict__ ctrl,
    float* __restrict__ out) {
  const int hbid = blockIdx.x;
  const int lid = ((hbid & 7) << 7) + (hbid >> 3);
  const int e = lid >> 7;
  const int ytile = (lid >> 2) & 31;
  const int d0 = (lid & 3) * 256;

  const int cnt = ctrl[e];
  if (ytile * 256 >= cnt) return;
  const int off = ctrl[8 + e];
  const int rows = min(256, cnt - ytile * 256);
  const int rbase = off + ytile * 256;

  __shared__ unsigned short sA[4][256 * 32];
  __shared__ unsigned short sW[4][256 * 32];

  const int tid = threadIdx.x;
  const int wv = tid >> 6, lane = tid & 63;
  const int cl = ((tid & 3) ^ ((tid >> 3) & 3)) * 8;

  const unsigned short* w3p = w3bt + (size_t)e * DIM * HID + (size_t)d0 * HID;
  const unsigned short* ga0 =
      act + (size_t)(rbase + min(tid >> 2, rows - 1)) * HID + cl;
  const unsigned short* ga1 =
      act + (size_t)(rbase + min(128 + (tid >> 2), rows - 1)) * HID + cl;
  const unsigned short* gw0 = w3p + (size_t)(tid >> 2) * HID + cl;
  const unsigned short* gw1 = w3p + (size_t)(128 + (tid >> 2)) * HID + cl;

  f32x4 acc[8][4];
#pragma unroll
  for (int i = 0; i < 8; i++)
#pragma unroll
    for (int jj = 0; jj < 4; jj++) acc[i][jj] = (f32x4){0.f, 0.f, 0.f, 0.f};

  const int wr = wv >> 2, wc = wv & 3;
  const int l15 = lane & 15, q = lane >> 4;
  const int pch = (q ^ ((l15 >> 1) & 3)) * 8;

#define S2A_STAGE(B)                                  \
  do {                                                \
    async16(ga0, sA[B] + (wv * 64) * 8);              \
    async16(ga1, sA[B] + (512 + wv * 64) * 8);        \
    async16(gw0, sW[B] + (wv * 64) * 8);              \
    async16(gw1, sW[B] + (512 + wv * 64) * 8);        \
    ga0 += 32; ga1 += 32; gw0 += 32; gw1 += 32;       \
  } while (0)

  S2A_STAGE(0); S2A_STAGE(1); S2A_STAGE(2);
  VM_WAIT(8);
  S_BARRIER;
  CFENCE;

  const int NT = HID / 32;
  for (int t = 0; t < NT; t++) {
    const int cur = t & 3;
    bf16x8 af[8], bf[4];
    {
      const unsigned short* as = sA[cur];
      const unsigned short* ws = sW[cur];
#pragma unroll
      for (int jj = 0; jj < 4; jj++)
        bf[jj] = *(const bf16x8*)(ws + (wc * 64 + jj * 16 + l15) * 32 + pch);
#pragma unroll
      for (int i = 0; i < 8; i++)
        af[i] = *(const bf16x8*)(as + (wr * 128 + i * 16 + l15) * 32 + pch);
    }
    if (t < NT - 3) {
      const int nb = (t + 3) & 3;
      S2A_STAGE(nb);
    }
    __builtin_amdgcn_s_setprio(1);
#pragma unroll
    for (int i = 0; i < 8; i++)
#pragma unroll
      for (int jj = 0; jj < 4; jj++)
        acc[i][jj] =
            __builtin_amdgcn_mfma_f32_16x16x32_bf16(af[i], bf[jj], acc[i][jj], 0, 0, 0);
    __builtin_amdgcn_s_setprio(0);
    LGKM0;
    __builtin_amdgcn_sched_barrier(0);
    if (t < NT - 3) VM_WAIT(8);
    else if (t == NT - 3) VM_WAIT(4);
    else if (t == NT - 2) VM_WAIT(0);
    CFENCE;
    S_BARRIER;
  }
#undef S2A_STAGE

#pragma unroll
  for (int i = 0; i < 8; i++)
#pragma unroll
    for (int rg = 0; rg < 4; rg++) {
      const int row = wr * 128 + i * 16 + q * 4 + rg;
      if (row < rows) {
        const int pr = rbase + row;
        const int tok = tok_list[pr];
        const float wt = pair_w[pr];
#pragma unroll
        for (int jj = 0; jj < 4; jj++) {
          const int dcol = d0 + wc * 64 + jj * 16 + l15;
          atomicAdd(out + (size_t)tok * DIM + dcol, (acc[i][jj][rg] + b3[e * DIM + dcol]) * wt);
        }
      }
    }
}

// ---------------------------------------------------------------------------
// combine: out[t] = pair_out[pos(t,0)] + pair_out[pos(t,1)]. grid NTOK x 256.
// ---------------------------------------------------------------------------
__global__ __launch_bounds__(256) void combine_kernel(
    const unsigned short* __restrict__ pair_out, const int* __restrict__ pair_pos,
    float* __restrict__ out) {
  const int t = blockIdx.x;
  const int d = threadIdx.x * 4;
  const int p0 = pair_pos[t * 2], p1 = pair_pos[t * 2 + 1];
  const ushort4 a = *(const ushort4*)(pair_out + (size_t)p0 * DIM + d);
  const ushort4 b = *(const ushort4*)(pair_out + (size_t)p1 * DIM + d);
  float4 r;
  r.x = bf2f(a.x) + bf2f(b.x);
  r.y = bf2f(a.y) + bf2f(b.y);
  r.z = bf2f(a.z) + bf2f(b.z);
  r.w = bf2f(a.w) + bf2f(b.w);
  *(float4*)(out + (size_t)t * DIM + d) = r;
}

// ---------------------------------------------------------------------------
// workspace layout (bytes)
// ---------------------------------------------------------------------------
static const size_t SZ_XB  = (size_t)NTOK * DIM * 2;        // 16 MB
static const size_t SZ_W   = (size_t)NE * DIM * HID * 2;    // 32 MB each
static const size_t SZ_ACT = (size_t)NPAIR * HID * 2;       // 64 MB
static const size_t OFF_XB  = 0;
static const size_t OFF_W1  = OFF_XB + SZ_XB;
static const size_t OFF_W2  = OFF_W1 + SZ_W;
static const size_t OFF_W3  = OFF_W2 + SZ_W;
static const size_t OFF_ACT = OFF_W3 + SZ_W;
static const size_t OFF_SC  = OFF_ACT + SZ_ACT;
static const size_t OFF_RE  = OFF_SC + (size_t)NTOK * NE * 4;
static const size_t OFF_RW  = OFF_RE + (size_t)NPAIR * 4;
static const size_t OFF_TL  = OFF_RW + (size_t)NPAIR * 4;
static const size_t OFF_PW  = OFF_TL + (size_t)NPAIR * 4;
static const size_t OFF_PP  = OFF_PW + (size_t)NPAIR * 4;
static const size_t OFF_CT  = OFF_PP + (size_t)NPAIR * 4;
static const size_t WS_BASE = OFF_CT + 128;
static const size_t OFF_PO  = WS_BASE;                      // pair_out bf16, 32 MB
static const size_t WS_FULL = OFF_PO + (size_t)NPAIR * DIM * 2;

extern "C" void kernel_launch(void* const* d_in, const int* in_sizes, int n_in,
                              void* d_out, int out_size, void* d_ws, size_t ws_size,
                              hipStream_t stream) {
  const float* x      = (const float*)d_in[0];
  const float* gate_w = (const float*)d_in[1];
  const float* gate_b = (const float*)d_in[2];
  const float* w1     = (const float*)d_in[3];
  const float* b1     = (const float*)d_in[4];
  const float* w2     = (const float*)d_in[5];
  const float* b2     = (const float*)d_in[6];
  const float* w3     = (const float*)d_in[7];
  const float* b3     = (const float*)d_in[8];
  float* out = (float*)d_out;

  if (ws_size < WS_BASE) {
    fprintf(stderr, "kernel_launch: ws_size %zu < needed %zu\n", ws_size, WS_BASE);
    return;
  }
  const bool store_path = (ws_size >= WS_FULL);

  char* ws = (char*)d_ws;
  unsigned short* xb   = (unsigned short*)(ws + OFF_XB);
  unsigned short* w1bt = (unsigned short*)(ws + OFF_W1);
  unsigned short* w2bt = (unsigned short*)(ws + OFF_W2);
  unsigned short* w3bt = (unsigned short*)(ws + OFF_W3);
  unsigned short* act  = (unsigned short*)(ws + OFF_ACT);
  float* scores        = (float*)(ws + OFF_SC);
  int* route_e         = (int*)(ws + OFF_RE);
  float* route_w       = (float*)(ws + OFF_RW);
  int* tok_list        = (int*)(ws + OFF_TL);
  float* pair_w        = (float*)(ws + OFF_PW);
  int* pair_pos        = (int*)(ws + OFF_PP);
  int* ctrl            = (int*)(ws + OFF_CT);
  unsigned short* pout = (unsigned short*)(ws + OFF_PO);

  if (!store_path)
    hipMemsetAsync(d_out, 0, (size_t)out_size * sizeof(float), stream);

  prepgate_kernel<<<14336, 256, 0, stream>>>(w1, w2, w3, w1bt, w2bt, w3bt,
                                             x, gate_w, gate_b, xb, scores,
                                             route_e, route_w);
  finalize_kernel<<<1, 1024, 0, stream>>>(scores, route_e, ctrl, out + (out_size - 1));
  scatter_kernel<<<32, 256, 0, stream>>>(route_e, route_w, ctrl, tok_list, pair_w,
                                         pair_pos);
  stage1_kernel<<<4096, 512, 0, stream>>>(xb, w1bt, w2bt, b1, b2, tok_list, ctrl, act);
  if (store_path) {
    stage2s_kernel<<<1024, 512, 0, stream>>>(act, w3bt, b3, pair_w, ctrl, pout);
    combine_kernel<<<NTOK, 256, 0, stream>>>(pout, pair_pos, out);
  } else {
    stage2a_kernel<<<1024, 512, 0, stream>>>(act, w3bt, b3, tok_list, pair_w,
                                             ctrl, out);
  }
}